// Round 2
// baseline (1211.532 us; speedup 1.0000x reference)
//
#include <hip/hip_runtime.h>
#include <math.h>

#define BB 128
#define T_TOT 1024    // T1*T2 = 128*8
#define DD 1024
#define EE 64
#define SPLIT 16      // blocks per batch row; grid = BB*SPLIT = 2048 = full residency
#define ROWS (T_TOT / SPLIT)  // 64 rows per block, as two 32-row streams

typedef float vfloat4 __attribute__((ext_vector_type(4)));

// ws layout:
//   [0, BB*SPLIT*DD) floats            : partial sums, 8 MiB
//   [BB*SPLIT*DD, +BB ints)            : per-batch arrival tickets (memset to 0
//                                        each iteration by a captured hipMemsetAsync)
//
// Single fused kernel. Phase 1: block (b,s) streams rows [64s, 64s+64) of batch
// b's [1024 x 1024] slab (nontemporal float4, two independent 32-row chains for
// MLP), writes its 1024-float partial. Then threadfence + ticket atomicAdd; the
// 16th arriver for batch b becomes the router block for b (standard last-block
// pattern, device-scope atomics -> XCD-safe). Router stages are the verified
// absmax=0.0 code from the baseline. Router work overlaps other batches' pool
// streaming; one launch + one kernel barrier removed vs the 2-kernel version.
__global__ __launch_bounds__(256) void fused_router(
    const float* __restrict__ x,
    const float* __restrict__ W_route, const float* __restrict__ b_route,
    const float* __restrict__ W_noise, const float* __restrict__ b_noise,
    const float* __restrict__ noise_eps, const int* __restrict__ mis_mask,
    float* __restrict__ part, int* __restrict__ tick,
    float* __restrict__ out /* [2*BB*EE]: router_output then noisy */) {
    __shared__ float s_pooled[DD];
    __shared__ float s_route[EE];
    __shared__ float s_noise[EE];
    __shared__ int   s_last;

    const int blk = blockIdx.x;
    const int b   = blk >> 4;           // / SPLIT
    const int s   = blk & (SPLIT - 1);  // % SPLIT
    const int tid = threadIdx.x;        // 0..255

    // ---- phase 1: partial pooling sum (thread t owns columns 4t..4t+3) ----
    {
        const vfloat4* p =
            (const vfloat4*)(x + ((size_t)b * T_TOT + (size_t)s * ROWS) * DD) + tid;
        vfloat4 a0 = (vfloat4)(0.f);
        vfloat4 a1 = (vfloat4)(0.f);
#pragma unroll 8
        for (int t = 0; t < ROWS / 2; ++t) {
            a0 += __builtin_nontemporal_load(&p[(size_t)t * (DD / 4)]);
            a1 += __builtin_nontemporal_load(&p[(size_t)(t + ROWS / 2) * (DD / 4)]);
        }
        ((vfloat4*)(part + (size_t)blk * DD))[tid] = a0 + a1;
    }

    // ---- arrival ticket: last block of batch b runs the router ----
    __threadfence();   // all threads: make partial stores device-visible
    __syncthreads();
    if (tid == 0) {
        const int old = atomicAdd(&tick[b], 1);  // device scope by default
        s_last = (old == SPLIT - 1) ? 1 : 0;
    }
    __syncthreads();
    if (!s_last) return;
    __threadfence();   // acquire: other blocks' partials now visible

    // ---- stage 1: pooled = mean over the 16 partials ----
    {
        vfloat4 acc = (vfloat4)(0.f);
#pragma unroll
        for (int q = 0; q < SPLIT; ++q) {
            acc += ((const vfloat4*)(part + (size_t)(b * SPLIT + q) * DD))[tid];
        }
        const float inv = 1.0f / (float)T_TOT;
        ((vfloat4*)s_pooled)[tid] = acc * inv;
    }
    __syncthreads();

    // ---- stage 2: dots. wave w -> experts [16w, 16w+16) ----
    {
        const int wave = tid >> 6;
        const int lane = tid & 63;
        for (int i = 0; i < 16; ++i) {
            const int e = wave * 16 + i;
            const float* wr = W_route + (size_t)e * DD;
            const float* wn = W_noise + (size_t)e * DD;
            float dr = 0.f, dn = 0.f;
#pragma unroll
            for (int j = 0; j < 16; ++j) {
                const float pv = s_pooled[lane + 64 * j];
                dr += pv * wr[lane + 64 * j];
                dn += pv * wn[lane + 64 * j];
            }
            for (int off = 32; off; off >>= 1) {
                dr += __shfl_down(dr, off, 64);
                dn += __shfl_down(dn, off, 64);
            }
            if (lane == 0) {
                s_route[e] = dr + b_route[e];
                s_noise[e] = dn + b_noise[e];
            }
        }
    }
    __syncthreads();

    // ---- stage 3: wave 0 only (64 lanes = 64 experts) ----
    if (tid < 64) {
        const int e = tid;

        // softmax over route logits
        float xv = s_route[e];
        float m = xv;
        for (int off = 32; off; off >>= 1) m = fmaxf(m, __shfl_xor(m, off, 64));
        float ex = expf(xv - m);
        float sum = ex;
        for (int off = 32; off; off >>= 1) sum += __shfl_xor(sum, off, 64);
        const float p_route = ex / sum;

        // noise path: softmax(noise_eps * softplus(noise_raw))
        const float nr = s_noise[e];
        const float sp = fmaxf(nr, 0.f) + log1pf(expf(-fabsf(nr)));  // stable softplus
        const float h  = noise_eps[b * EE + e] * sp;
        float m2 = h;
        for (int off = 32; off; off >>= 1) m2 = fmaxf(m2, __shfl_xor(m2, off, 64));
        float ex2 = expf(h - m2);
        float sum2 = ex2;
        for (int off = 32; off; off >>= 1) sum2 += __shfl_xor(sum2, off, 64);
        const float p_noise = ex2 / sum2;

        const float noisy = p_route + p_noise;
        out[(size_t)(BB * EE) + b * EE + e] = noisy;  // output 1

        // rank(e) under jax.lax.top_k (descending, stable ties by index)
        const int k = mis_mask[b];
        int cnt = 0;
        for (int j = 0; j < 64; ++j) {
            const float vj = __shfl(noisy, j, 64);
            cnt += (vj > noisy) || (vj == noisy && j < e);
        }
        float sparse = (cnt < k) ? noisy : 0.f;
        // reference quirk: padded rows (k < E) force expert 0's slot to 0
        if (e == 0 && k < EE) sparse = 0.f;

        // final softmax over sparse
        float m3 = sparse;
        for (int off = 32; off; off >>= 1) m3 = fmaxf(m3, __shfl_xor(m3, off, 64));
        float ex3 = expf(sparse - m3);
        float sum3 = ex3;
        for (int off = 32; off; off >>= 1) sum3 += __shfl_xor(sum3, off, 64);
        out[b * EE + e] = ex3 / sum3;  // output 0
    }
}

extern "C" void kernel_launch(void* const* d_in, const int* in_sizes, int n_in,
                              void* d_out, int out_size, void* d_ws, size_t ws_size,
                              hipStream_t stream) {
    const float* mh        = (const float*)d_in[0];  // [128,128,8,1024]
    const float* W_route   = (const float*)d_in[1];  // [64,1024]
    const float* b_route   = (const float*)d_in[2];  // [64]
    const float* W_noise   = (const float*)d_in[3];  // [64,1024]
    const float* b_noise   = (const float*)d_in[4];  // [64]
    const float* noise_eps = (const float*)d_in[5];  // [128,64]
    const int*   mis_mask  = (const int*)d_in[6];    // [128]
    float* out  = (float*)d_out;                     // [2*128*64]
    float* part = (float*)d_ws;                      // 8 MiB partials
    int*   tick = (int*)((float*)d_ws + (size_t)BB * SPLIT * DD);

    // zero the 128 arrival tickets (512 B) — stream-ordered, graph-capturable
    hipMemsetAsync(tick, 0, BB * sizeof(int), stream);

    fused_router<<<BB * SPLIT, 256, 0, stream>>>(mh, W_route, b_route,
                                                 W_noise, b_noise, noise_eps,
                                                 mis_mask, part, tick, out);
}